// Round 1
// baseline (165.648 us; speedup 1.0000x reference)
//
#include <hip/hip_runtime.h>
#include <hip/hip_bf16.h>
#include <math.h>

#define B_ 4
#define S_ 4096
#define E_ 1024

typedef __attribute__((ext_vector_type(8))) short bf16x8;
typedef __attribute__((ext_vector_type(4))) short bf16x4;
typedef __attribute__((ext_vector_type(4))) float f32x4;

__device__ __forceinline__ unsigned short f2bf(float f) {
  unsigned u = __float_as_uint(f);
  u = u + 0x7fffu + ((u >> 16) & 1u);
  return (unsigned short)(u >> 16);
}

// ---------------- projection: Q/K/Vt = x @ W^T ----------------
// x [16384][1024] f32 ; Wq/Wk/Wv [64][1024] f32
// Qp [16384][64] bf16 (pre-scaled by log2(e)/32), Kb [16384][64] bf16,
// Vt [4][64][4096] bf16 (V transposed per batch)
__global__ __launch_bounds__(256) void proj_kernel(
    const float* __restrict__ x, const float* __restrict__ Wq,
    const float* __restrict__ Wk, const float* __restrict__ Wv,
    unsigned short* __restrict__ Qp, unsigned short* __restrict__ Kb,
    unsigned short* __restrict__ Vt)
{
  __shared__ __align__(16) unsigned short xs[64*64];   // [64 m][64 k] bf16, XOR-swizzled
  __shared__ __align__(16) unsigned short wl[192*64];  // [192 n][64 k] bf16, XOR-swizzled
  const int tid = threadIdx.x;
  const int wave = tid >> 6, lane = tid & 63;
  const int l15 = lane & 15, l4 = lane >> 4;
  const int m0 = blockIdx.x * 64;

  f32x4 acc[12];
  #pragma unroll
  for (int i = 0; i < 12; i++) acc[i] = (f32x4)0.f;

  f32x4 xr[4], wr[12];
  // prefetch k-step 0
  #pragma unroll
  for (int i = 0; i < 4; i++) {
    int c = tid + i*256; int row = c >> 4, cc = c & 15;
    xr[i] = *(const f32x4*)(x + (size_t)(m0 + row)*E_ + cc*4);
  }
  #pragma unroll
  for (int i = 0; i < 12; i++) {
    int c = tid + i*256; int n = c >> 4, cc = c & 15;
    const float* Wsrc = (n < 64) ? (Wq + (size_t)n*E_)
                     : ((n < 128) ? (Wk + (size_t)(n-64)*E_)
                                  : (Wv + (size_t)(n-128)*E_));
    wr[i] = *(const f32x4*)(Wsrc + cc*4);
  }

  for (int ks = 0; ks < 16; ks++) {
    __syncthreads();
    // write staged regs -> LDS (fp32 -> bf16, swizzled)
    #pragma unroll
    for (int i = 0; i < 4; i++) {
      int c = tid + i*256; int row = c >> 4, cc = c & 15;
      bf16x4 v;
      v[0] = (short)f2bf(xr[i][0]); v[1] = (short)f2bf(xr[i][1]);
      v[2] = (short)f2bf(xr[i][2]); v[3] = (short)f2bf(xr[i][3]);
      *(bf16x4*)((char*)xs + row*128 + ((cc*8) ^ ((row&7)<<4))) = v;
    }
    #pragma unroll
    for (int i = 0; i < 12; i++) {
      int c = tid + i*256; int n = c >> 4, cc = c & 15;
      bf16x4 v;
      v[0] = (short)f2bf(wr[i][0]); v[1] = (short)f2bf(wr[i][1]);
      v[2] = (short)f2bf(wr[i][2]); v[3] = (short)f2bf(wr[i][3]);
      *(bf16x4*)((char*)wl + n*128 + ((cc*8) ^ ((n&7)<<4))) = v;
    }
    // prefetch next k-step
    if (ks < 15) {
      #pragma unroll
      for (int i = 0; i < 4; i++) {
        int c = tid + i*256; int row = c >> 4, cc = c & 15;
        xr[i] = *(const f32x4*)(x + (size_t)(m0 + row)*E_ + (ks+1)*64 + cc*4);
      }
      #pragma unroll
      for (int i = 0; i < 12; i++) {
        int c = tid + i*256; int n = c >> 4, cc = c & 15;
        const float* Wsrc = (n < 64) ? (Wq + (size_t)n*E_)
                         : ((n < 128) ? (Wk + (size_t)(n-64)*E_)
                                      : (Wv + (size_t)(n-128)*E_));
        wr[i] = *(const f32x4*)(Wsrc + (ks+1)*64 + cc*4);
      }
    }
    __syncthreads();
    // compute: wave's 16 rows x 192 cols
    const int arow = wave*16 + l15;
    const int aswz = (arow&7)<<4;
    bf16x8 a0 = *(const bf16x8*)((const char*)xs + arow*128 + ((l4*16) ^ aswz));
    bf16x8 a1 = *(const bf16x8*)((const char*)xs + arow*128 + ((64 + l4*16) ^ aswz));
    #pragma unroll
    for (int ntl = 0; ntl < 12; ntl++) {
      int brow = ntl*16 + l15;
      int bswz = (brow&7)<<4;
      bf16x8 b0 = *(const bf16x8*)((const char*)wl + brow*128 + ((l4*16) ^ bswz));
      bf16x8 b1 = *(const bf16x8*)((const char*)wl + brow*128 + ((64 + l4*16) ^ bswz));
      acc[ntl] = __builtin_amdgcn_mfma_f32_16x16x32_bf16(a0, b0, acc[ntl], 0, 0, 0);
      acc[ntl] = __builtin_amdgcn_mfma_f32_16x16x32_bf16(a1, b1, acc[ntl], 0, 0, 0);
    }
  }

  // epilogue: D layout col=l&15, row=(l>>4)*4+r
  const float QSC = 0.04508422f;  // log2(e) / sqrt(1024)
  const int mb = m0 + wave*16 + l4*4;
  #pragma unroll
  for (int ntl = 0; ntl < 4; ntl++) {
    int col = ntl*16 + l15;
    #pragma unroll
    for (int r = 0; r < 4; r++)
      Qp[(size_t)(mb + r)*64 + col] = f2bf(acc[ntl][r] * QSC);
  }
  #pragma unroll
  for (int ntl = 0; ntl < 4; ntl++) {
    int col = ntl*16 + l15;
    #pragma unroll
    for (int r = 0; r < 4; r++)
      Kb[(size_t)(mb + r)*64 + col] = f2bf(acc[4+ntl][r]);
  }
  const int b = m0 >> 12;
  const int sb = (m0 & 4095) + wave*16 + l4*4;
  #pragma unroll
  for (int ntl = 0; ntl < 4; ntl++) {
    int d = ntl*16 + l15;
    bf16x4 v;
    #pragma unroll
    for (int r = 0; r < 4; r++) v[r] = (short)f2bf(acc[8+ntl][r]);
    *(bf16x4*)(Vt + (size_t)(b*64 + d)*S_ + sb) = v;
  }
}

// ---------------- causal flash attention ----------------
// Swapped-QK^T: S^T = K x Q^T, lane owns q = lane&15 (+16*group).
// O accumulated transposed: O^T = V^T x P^T.
// Block = (batch, pair p): processes q-blocks j=p and j=127-p (QBLK=32)
// -> uniform 65 KV-tiles per block. 4 waves = 2 q-groups x 2 k-halves,
// flash-merge of the halves through LDS at the end.
__global__ __launch_bounds__(256) void attn_kernel(
    const unsigned short* __restrict__ Qp,
    const unsigned short* __restrict__ Kb,
    const unsigned short* __restrict__ Vt,
    float* __restrict__ out)
{
  __shared__ __align__(16) unsigned short Ks[64*64];  // [64 k][64 d], swizzled
  __shared__ __align__(16) unsigned short Vs[64*64];  // [64 d][64 k], swizzled
  __shared__ __align__(16) float mergeO[4][16][64];
  __shared__ float mstats[4][16][2];

  const int tid = threadIdx.x;
  const int wave = tid >> 6, lane = tid & 63;
  const int l15 = lane & 15, l4 = lane >> 4;
  const int g = wave >> 1, h = wave & 1;
  const int b = blockIdx.x >> 6;
  const int p = blockIdx.x & 63;

  const unsigned short* Qb  = Qp + (size_t)b*S_*64;
  const unsigned short* Kbb = Kb + (size_t)b*S_*64;
  const unsigned short* Vtb = Vt + (size_t)b*64*S_;
  float* outb = out + (size_t)b*S_*64;

  #pragma unroll 1
  for (int half = 0; half < 2; half++) {
    const int jq = half ? (127 - p) : p;
    const int q0 = jq * 32;
    const int ntile = (jq >> 1) + 1;
    const int qrow = q0 + g*16 + l15;

    bf16x8 qf0 = *(const bf16x8*)(Qb + (size_t)qrow*64 + l4*8);
    bf16x8 qf1 = *(const bf16x8*)(Qb + (size_t)qrow*64 + 32 + l4*8);

    float m = -INFINITY, lsum = 0.f;
    f32x4 acc[4];
    #pragma unroll
    for (int i = 0; i < 4; i++) acc[i] = (f32x4)0.f;

    f32x4 kreg[2], vreg[2];
    // prefetch KV tile 0
    #pragma unroll
    for (int i = 0; i < 2; i++) {
      int c = tid + i*256; int row = c >> 3, cc = c & 7;
      kreg[i] = *(const f32x4*)((const char*)Kbb + (size_t)row*128 + cc*16);
      vreg[i] = *(const f32x4*)((const char*)Vtb + (size_t)row*8192 + cc*16);
    }

    for (int t = 0; t < ntile; t++) {
      __syncthreads();
      // regs -> LDS (swizzled)
      #pragma unroll
      for (int i = 0; i < 2; i++) {
        int c = tid + i*256; int row = c >> 3, cc = c & 7;
        *(f32x4*)((char*)Ks + row*128 + ((cc*16) ^ ((row&7)<<4))) = kreg[i];
        *(f32x4*)((char*)Vs + row*128 + ((cc*16) ^ ((row&7)<<4))) = vreg[i];
      }
      // prefetch next tile
      if (t + 1 < ntile) {
        int k0 = (t+1)*64;
        #pragma unroll
        for (int i = 0; i < 2; i++) {
          int c = tid + i*256; int row = c >> 3, cc = c & 7;
          kreg[i] = *(const f32x4*)((const char*)Kbb + (size_t)(k0+row)*128 + cc*16);
          vreg[i] = *(const f32x4*)((const char*)Vtb + (size_t)row*8192 + (size_t)k0*2 + cc*16);
        }
      }
      __syncthreads();

      // QK^T (this wave's 32-key half: subtiles 2h, 2h+1)
      f32x4 sv[2];
      #pragma unroll
      for (int st = 0; st < 2; st++) {
        int krow = (2*h + st)*16 + l15;
        const char* kbp = (const char*)Ks + krow*128;
        int swz = (krow&7)<<4;
        bf16x8 k0f = *(const bf16x8*)(kbp + ((l4*16) ^ swz));
        bf16x8 k1f = *(const bf16x8*)(kbp + ((64 + l4*16) ^ swz));
        f32x4 z = (f32x4)0.f;
        z = __builtin_amdgcn_mfma_f32_16x16x32_bf16(k0f, qf0, z, 0, 0, 0);
        z = __builtin_amdgcn_mfma_f32_16x16x32_bf16(k1f, qf1, z, 0, 0, 0);
        sv[st] = z;
      }
      // causal mask on the diagonal tile
      if (t == ntile - 1) {
        #pragma unroll
        for (int st = 0; st < 2; st++) {
          #pragma unroll
          for (int r = 0; r < 4; r++) {
            int kg = t*64 + (2*h + st)*16 + l4*4 + r;
            if (kg > qrow) sv[st][r] = -INFINITY;
          }
        }
      }
      // online softmax (base-2; Q pre-scaled by log2e/sqrt(E))
      float pmax = sv[0][0];
      #pragma unroll
      for (int st = 0; st < 2; st++) {
        #pragma unroll
        for (int r = 0; r < 4; r++) pmax = fmaxf(pmax, sv[st][r]);
      }
      pmax = fmaxf(pmax, __shfl_xor(pmax, 16, 64));
      pmax = fmaxf(pmax, __shfl_xor(pmax, 32, 64));
      float mnew = fmaxf(m, pmax);
      float msafe = (mnew == -INFINITY) ? 0.f : mnew;  // fully-masked half guard
      float scale = exp2f(m - msafe);
      float pv[8]; float psum = 0.f;
      #pragma unroll
      for (int i = 0; i < 8; i++) {
        pv[i] = exp2f(sv[i>>2][i&3] - msafe);
        psum += pv[i];
      }
      psum += __shfl_xor(psum, 16, 64);
      psum += __shfl_xor(psum, 32, 64);
      lsum = lsum*scale + psum;
      m = mnew;
      #pragma unroll
      for (int i = 0; i < 4; i++) acc[i] *= scale;
      // P -> bf16 A/B fragment (k = l4*4 + (i&3) + 16*(i>>2) within half)
      bf16x8 pf;
      #pragma unroll
      for (int i = 0; i < 8; i++) pf[i] = (short)f2bf(pv[i]);
      // O^T += V^T x P^T over this wave's k-half
      #pragma unroll
      for (int dt = 0; dt < 4; dt++) {
        int drow = dt*16 + l15;
        const char* vb = (const char*)Vs + drow*128;
        int swz = (drow&7)<<4;
        bf16x4 v0 = *(const bf16x4*)(vb + ((h*64 + l4*8) ^ swz));
        bf16x4 v1 = *(const bf16x4*)(vb + ((h*64 + 32 + l4*8) ^ swz));
        bf16x8 vf;
        #pragma unroll
        for (int i = 0; i < 4; i++) { vf[i] = v0[i]; vf[i+4] = v1[i]; }
        acc[dt] = __builtin_amdgcn_mfma_f32_16x16x32_bf16(vf, pf, acc[dt], 0, 0, 0);
      }
    } // KV tiles

    // merge the two k-half partials, normalize, store
    __syncthreads();
    #pragma unroll
    for (int dt = 0; dt < 4; dt++)
      *(f32x4*)&mergeO[wave][l15][dt*16 + l4*4] = acc[dt];
    if (lane < 16) { mstats[wave][lane][0] = m; mstats[wave][lane][1] = lsum; }
    __syncthreads();
    {
      int ql = tid >> 3, dc = tid & 7;
      int gg = ql >> 4, q16 = ql & 15;
      float m1 = mstats[gg*2+0][q16][0], s1 = mstats[gg*2+0][q16][1];
      float m2 = mstats[gg*2+1][q16][0], s2 = mstats[gg*2+1][q16][1];
      float m12 = fmaxf(m1, m2);
      float a1 = exp2f(m1 - m12), a2 = exp2f(m2 - m12);
      float inv = 1.f / (s1*a1 + s2*a2);
      a1 *= inv; a2 *= inv;
      #pragma unroll
      for (int i = 0; i < 2; i++) {
        int d = dc*8 + i*4;
        f32x4 o1 = *(const f32x4*)&mergeO[gg*2+0][q16][d];
        f32x4 o2 = *(const f32x4*)&mergeO[gg*2+1][q16][d];
        f32x4 o = o1*a1 + o2*a2;
        *(f32x4*)(outb + (size_t)(q0 + ql)*64 + d) = o;
      }
    }
  } // half
}

extern "C" void kernel_launch(void* const* d_in, const int* in_sizes, int n_in,
                              void* d_out, int out_size, void* d_ws, size_t ws_size,
                              hipStream_t stream)
{
  const float* x  = (const float*)d_in[0];
  const float* Wq = (const float*)d_in[1];
  const float* Wk = (const float*)d_in[2];
  const float* Wv = (const float*)d_in[3];
  unsigned short* Qp  = (unsigned short*)d_ws;                 // 2 MB
  unsigned short* Kbp = Qp  + (size_t)B_*S_*64;                // 2 MB
  unsigned short* Vtp = Kbp + (size_t)B_*S_*64;                // 2 MB
  float* out = (float*)d_out;

  hipLaunchKernelGGL(proj_kernel, dim3(256), dim3(256), 0, stream,
                     x, Wq, Wk, Wv, Qp, Kbp, Vtp);
  hipLaunchKernelGGL(attn_kernel, dim3(256), dim3(256), 0, stream,
                     Qp, Kbp, Vtp, out);
}